// Round 1
// baseline (1433.997 us; speedup 1.0000x reference)
//
#include <hip/hip_runtime.h>
#include <hip/hip_bf16.h>
#include <math.h>

#define HID 128
#define HEADS 8
#define HC 16
#define INDIM 64

// ---------------- embed: h = x @ emb_W + emb_b + ntype_emb[node_types] ----------------
// 4 nodes per 128-thread block; thread t owns output channel t for all 4 nodes.
__global__ void embed_kernel(const float* __restrict__ x, const float* __restrict__ W,
                             const float* __restrict__ b, const float* __restrict__ nemb,
                             const int* __restrict__ ntypes, float* __restrict__ h, int N) {
    int t = threadIdx.x;           // 0..127
    int n0 = blockIdx.x * 4;
    __shared__ float xr[4][INDIM];
    // load 4 rows of x (4*64 = 256 elems, 128 threads -> 2 each)
    for (int i = t; i < 4 * INDIM; i += 128) {
        int j = i >> 6, k = i & 63;
        int n = n0 + j;
        xr[j][k] = (n < N) ? x[n * INDIM + k] : 0.f;
    }
    __syncthreads();
    float acc[4] = {0.f, 0.f, 0.f, 0.f};
#pragma unroll 8
    for (int k = 0; k < INDIM; ++k) {
        float w = W[k * HID + t];
#pragma unroll
        for (int j = 0; j < 4; ++j) acc[j] += xr[j][k] * w;
    }
    float bb = b[t];
#pragma unroll
    for (int j = 0; j < 4; ++j) {
        int n = n0 + j;
        if (n < N) {
            int nt = ntypes[n];
            h[n * HID + t] = acc[j] + bb + nemb[nt * HID + t];
        }
    }
}

// ---------------- GAT projection + per-node attention logits ----------------
// hp = h @ W ; alpha_s[n,hd] = sum_c hp[n,hd,c]*a_src[hd,c] ; same for dst.
__global__ void gemm_alpha_kernel(const float* __restrict__ h, const float* __restrict__ W,
                                  const float* __restrict__ asrc, const float* __restrict__ adst,
                                  float* __restrict__ hp, float* __restrict__ als,
                                  float* __restrict__ ald, int N) {
    int t = threadIdx.x;           // 0..127
    int n0 = blockIdx.x * 4;
    __shared__ float hr[4][HID];
#pragma unroll
    for (int j = 0; j < 4; ++j) {
        int n = n0 + j;
        hr[j][t] = (n < N) ? h[n * HID + t] : 0.f;
    }
    __syncthreads();
    float acc[4] = {0.f, 0.f, 0.f, 0.f};
#pragma unroll 8
    for (int k = 0; k < HID; ++k) {
        float w = W[k * HID + t];
#pragma unroll
        for (int j = 0; j < 4; ++j) acc[j] += hr[j][k] * w;
    }
    float as = asrc[t], ad = adst[t];
#pragma unroll
    for (int j = 0; j < 4; ++j) {
        int n = n0 + j;
        if (n >= N) continue;
        hp[n * HID + t] = acc[j];
        float ps = acc[j] * as;
        float pd = acc[j] * ad;
        // reduce within the 16 lanes of each head (16-aligned groups inside a wave)
#pragma unroll
        for (int m = 8; m >= 1; m >>= 1) {
            ps += __shfl_xor(ps, m, 64);
            pd += __shfl_xor(pd, m, 64);
        }
        if ((t & 15) == 0) {
            int hd = t >> 4;
            als[n * HEADS + hd] = ps;
            ald[n * HEADS + hd] = pd;
        }
    }
}

// ---------------- edge pass 1: softmax denominators ----------------
// w = exp(leaky_relu(as[src]+ad[dst])); s[dst,hd] += w   (no max-subtraction: logits bounded)
__global__ void edge_w_kernel(const int* __restrict__ ei, const float* __restrict__ als,
                              const float* __restrict__ ald, float* __restrict__ s,
                              int E, int EE) {
    int idx = blockIdx.x * blockDim.x + threadIdx.x;  // over EE*HEADS
    if (idx >= EE * HEADS) return;
    int e = idx >> 3, hd = idx & 7;
    int src, dst;
    if (e < E) { src = ei[e]; dst = ei[E + e]; } else { src = dst = e - E; }
    float v = als[src * HEADS + hd] + ald[dst * HEADS + hd];
    v = v > 0.f ? v : 0.2f * v;
    atomicAdd(&s[dst * HEADS + hd], __expf(v));
}

// ---------------- edge pass 2: weighted message aggregation (numerator) ----------------
__global__ void edge_msg_kernel(const int* __restrict__ ei, const float* __restrict__ als,
                                const float* __restrict__ ald, const float* __restrict__ hp,
                                float* __restrict__ outacc, int E, int EE) {
    int idx = blockIdx.x * blockDim.x + threadIdx.x;  // over EE*HID (83.2M < 2^31)
    if (idx >= EE * HID) return;
    int e = idx >> 7, c = idx & 127;
    int hd = c >> 4;
    int src, dst;
    if (e < E) { src = ei[e]; dst = ei[E + e]; } else { src = dst = e - E; }
    float v = als[src * HEADS + hd] + ald[dst * HEADS + hd];
    v = v > 0.f ? v : 0.2f * v;
    float w = __expf(v);
    atomicAdd(&outacc[dst * HID + c], w * hp[src * HID + c]);
}

// ---------------- finalize: divide, +bias, layernorm, residual relu ----------------
// one 64-lane wave per node, 2 channels per lane; 4 nodes per 256-thread block
__global__ void finalize_kernel(const float* __restrict__ outacc, const float* __restrict__ s,
                                const float* __restrict__ gb, const float* __restrict__ lg,
                                const float* __restrict__ lb, float* __restrict__ h, int N) {
    int wave = threadIdx.x >> 6;
    int lane = threadIdx.x & 63;
    int n = blockIdx.x * 4 + wave;
    if (n >= N) return;
    int c0 = lane, c1 = lane + 64;
    float v0 = outacc[n * HID + c0] / s[n * HEADS + (c0 >> 4)] + gb[c0];
    float v1 = outacc[n * HID + c1] / s[n * HEADS + (c1 >> 4)] + gb[c1];
    float sum = v0 + v1;
#pragma unroll
    for (int m = 32; m >= 1; m >>= 1) sum += __shfl_xor(sum, m, 64);
    float mu = sum * (1.f / 128.f);
    float d0 = v0 - mu, d1 = v1 - mu;
    float sq = d0 * d0 + d1 * d1;
#pragma unroll
    for (int m = 32; m >= 1; m >>= 1) sq += __shfl_xor(sq, m, 64);
    float inv = rsqrtf(sq * (1.f / 128.f) + 1e-5f);
    float y0 = d0 * inv * lg[c0] + lb[c0];
    float y1 = d1 * inv * lg[c1] + lb[c1];
    float r0 = y0 + h[n * HID + c0];
    float r1 = y1 + h[n * HID + c1];
    h[n * HID + c0] = r0 > 0.f ? r0 : 0.f;
    h[n * HID + c1] = r1 > 0.f ? r1 : 0.f;
}

// ---------------- global attention scores: escore[n] = exp(tanh(h@W1+b1)@W2 + b2) ----------------
__global__ void score_kernel(const float* __restrict__ h, const float* __restrict__ W1,
                             const float* __restrict__ b1, const float* __restrict__ W2,
                             const float* __restrict__ b2, float* __restrict__ escore, int N) {
    int t = threadIdx.x;           // 0..127
    int n0 = blockIdx.x * 4;
    __shared__ float hr[4][HID];
    __shared__ float part[4][2];
#pragma unroll
    for (int j = 0; j < 4; ++j) {
        int n = n0 + j;
        hr[j][t] = (n < N) ? h[n * HID + t] : 0.f;
    }
    __syncthreads();
    float acc[4];
#pragma unroll
    for (int j = 0; j < 4; ++j) acc[j] = b1[t];
#pragma unroll 8
    for (int k = 0; k < HID; ++k) {
        float w = W1[k * HID + t];
#pragma unroll
        for (int j = 0; j < 4; ++j) acc[j] += hr[j][k] * w;
    }
    float w2 = W2[t];
#pragma unroll
    for (int j = 0; j < 4; ++j) {
        float v = tanhf(acc[j]) * w2;
#pragma unroll
        for (int m = 32; m >= 1; m >>= 1) v += __shfl_xor(v, m, 64);
        if ((t & 63) == 0) part[j][t >> 6] = v;
    }
    __syncthreads();
    if (t < 4) {
        int n = n0 + t;
        if (n < N) escore[n] = expf(part[t][0] + part[t][1] + b2[0]);
    }
}

// ---------------- pooling: global-attention numerator/denominator + per-graph mean pool ----------------
__global__ void pool_kernel(const float* __restrict__ h, const float* __restrict__ escore,
                            const int* __restrict__ batch, float* __restrict__ sums,
                            float* __restrict__ cnts, float* __restrict__ hgZ, int N) {
    __shared__ float lh[HID];
    __shared__ float lz;
    int t = threadIdx.x;
    if (t < HID) lh[t] = 0.f;
    if (t == 0) lz = 0.f;
    __syncthreads();
    int total = N * HID;
    int stride = gridDim.x * blockDim.x;   // multiple of 128 -> c fixed per thread
    for (int idx = blockIdx.x * blockDim.x + t; idx < total; idx += stride) {
        int n = idx >> 7, c = idx & 127;
        float hv = h[idx];
        float es = escore[n];
        atomicAdd(&lh[c], es * hv);
        int b = batch[n];
        atomicAdd(&sums[b * HID + c], hv);
        if (c == 0) {
            atomicAdd(&lz, es);
            atomicAdd(&cnts[b], 1.0f);
        }
    }
    __syncthreads();
    if (t < HID) atomicAdd(&hgZ[t], lh[t]);
    if (t == 0) atomicAdd(&hgZ[HID], lz);
}

// ---------------- classifier head: one graph per 128-thread block ----------------
__global__ void head_kernel(const float* __restrict__ hgZ, const float* __restrict__ sums,
                            const float* __restrict__ cnts, const float* __restrict__ W1,
                            const float* __restrict__ b1, const float* __restrict__ W2,
                            const float* __restrict__ b2, float* __restrict__ out, int G) {
    int g = blockIdx.x;
    int t = threadIdx.x;
    __shared__ float hr[HID];
    __shared__ float part[2];
    float Z = hgZ[HID];
    float cnt = cnts[g];
    cnt = cnt > 1.f ? cnt : 1.f;
    hr[t] = hgZ[t] / Z + sums[g * HID + t] / cnt;
    __syncthreads();
    float acc = b1[t];
#pragma unroll 8
    for (int k = 0; k < HID; ++k) acc += hr[k] * W1[k * HID + t];
    acc = acc > 0.f ? acc : 0.f;
    float v = acc * W2[t];
#pragma unroll
    for (int m = 32; m >= 1; m >>= 1) v += __shfl_xor(v, m, 64);
    if ((t & 63) == 0) part[t >> 6] = v;
    __syncthreads();
    if (t == 0) out[g] = part[0] + part[1] + b2[0];
}

extern "C" void kernel_launch(void* const* d_in, const int* in_sizes, int n_in,
                              void* d_out, int out_size, void* d_ws, size_t ws_size,
                              hipStream_t stream) {
    const float* x        = (const float*)d_in[0];
    const int*   ei       = (const int*)d_in[1];
    const int*   ntypes   = (const int*)d_in[2];
    const int*   batch    = (const int*)d_in[3];
    const float* emb_W    = (const float*)d_in[4];
    const float* emb_b    = (const float*)d_in[5];
    const float* nemb     = (const float*)d_in[6];
    const float* gat_W    = (const float*)d_in[7];
    const float* att_src  = (const float*)d_in[8];
    const float* att_dst  = (const float*)d_in[9];
    const float* gat_b    = (const float*)d_in[10];
    const float* ln_g     = (const float*)d_in[11];
    const float* ln_b     = (const float*)d_in[12];
    const float* ga_W1    = (const float*)d_in[13];
    const float* ga_b1    = (const float*)d_in[14];
    const float* ga_W2    = (const float*)d_in[15];
    const float* ga_b2    = (const float*)d_in[16];
    const float* cls_W1   = (const float*)d_in[17];
    const float* cls_b1   = (const float*)d_in[18];
    const float* cls_W2   = (const float*)d_in[19];
    const float* cls_b2   = (const float*)d_in[20];
    float* out = (float*)d_out;

    const int N  = in_sizes[2];
    const int E  = in_sizes[1] / 2;
    const int EE = E + N;
    const int G  = out_size;

    float* ws      = (float*)d_ws;
    float* h       = ws;                               // N*128
    float* hp      = h + (size_t)N * HID;              // N*128
    float* outacc  = hp + (size_t)N * HID;             // N*128
    float* als     = outacc + (size_t)N * HID;         // N*8
    float* ald     = als + (size_t)N * HEADS;          // N*8
    float* s       = ald + (size_t)N * HEADS;          // N*8
    float* escore  = s + (size_t)N * HEADS;            // N
    float* sums    = escore + N;                       // G*128
    float* cnts    = sums + (size_t)G * HID;           // G
    float* hgZ     = cnts + G;                         // 129

    embed_kernel<<<(N + 3) / 4, 128, 0, stream>>>(x, emb_W, emb_b, nemb, ntypes, h, N);

    for (int l = 0; l < 3; ++l) {
        hipMemsetAsync(outacc, 0, (size_t)N * HID * sizeof(float), stream);
        hipMemsetAsync(s, 0, (size_t)N * HEADS * sizeof(float), stream);
        gemm_alpha_kernel<<<(N + 3) / 4, 128, 0, stream>>>(
            h, gat_W + (size_t)l * HID * HID, att_src + l * HID, att_dst + l * HID,
            hp, als, ald, N);
        int nw = EE * HEADS;
        edge_w_kernel<<<(nw + 255) / 256, 256, 0, stream>>>(ei, als, ald, s, E, EE);
        int nm = EE * HID;
        edge_msg_kernel<<<(nm + 255) / 256, 256, 0, stream>>>(ei, als, ald, hp, outacc, E, EE);
        finalize_kernel<<<(N + 3) / 4, 256, 0, stream>>>(
            outacc, s, gat_b + l * HID, ln_g + l * HID, ln_b + l * HID, h, N);
    }

    score_kernel<<<(N + 3) / 4, 128, 0, stream>>>(h, ga_W1, ga_b1, ga_W2, ga_b2, escore, N);
    hipMemsetAsync(sums, 0, ((size_t)G * HID + G + HID + 1) * sizeof(float), stream);
    pool_kernel<<<512, 256, 0, stream>>>(h, escore, batch, sums, cnts, hgZ, N);
    head_kernel<<<G, 128, 0, stream>>>(hgZ, sums, cnts, cls_W1, cls_b1, cls_W2, cls_b2, out, G);
}

// Round 2
// 696.788 us; speedup vs baseline: 2.0580x; 2.0580x over previous
//
#include <hip/hip_runtime.h>
#include <hip/hip_bf16.h>
#include <math.h>

#define HID 128
#define HEADS 8
#define INDIM 64

// ================= CSR build (by dst) =================

__global__ void count_kernel(const int* __restrict__ ei, int* __restrict__ deg, int E, int EE) {
    int e = blockIdx.x * blockDim.x + threadIdx.x;
    if (e >= EE) return;
    int dst = (e < E) ? ei[E + e] : (e - E);
    atomicAdd(&deg[dst], 1);
}

// per-256-chunk sums of deg
__global__ void block_sum_kernel(const int* __restrict__ deg, int* __restrict__ partials, int N) {
    __shared__ int sdata[4];
    int t = threadIdx.x;
    int i = blockIdx.x * 256 + t;
    int v = (i < N) ? deg[i] : 0;
#pragma unroll
    for (int m = 32; m >= 1; m >>= 1) v += __shfl_xor(v, m, 64);
    if ((t & 63) == 0) sdata[t >> 6] = v;
    __syncthreads();
    if (t == 0) partials[blockIdx.x] = sdata[0] + sdata[1] + sdata[2] + sdata[3];
}

// exclusive scan of partials in-place (single wave, handles any nb)
__global__ void scan_partials_kernel(int* __restrict__ partials, int nb) {
    int lane = threadIdx.x;  // 64 threads
    int carry = 0;
    for (int base = 0; base < nb; base += 64) {
        int i = base + lane;
        int v = (i < nb) ? partials[i] : 0;
        int orig = v;
#pragma unroll
        for (int off = 1; off < 64; off <<= 1) {
            int x = __shfl_up(v, off, 64);
            if (lane >= off) v += x;
        }
        if (i < nb) partials[i] = v - orig + carry;
        carry += __shfl(v, 63, 64);
    }
}

// per-chunk exclusive scan + partials offset -> rowptr, woff
__global__ void rowptr_kernel(const int* __restrict__ deg, const int* __restrict__ partials,
                              int* __restrict__ rowptr, int* __restrict__ woff, int N, int EE) {
    __shared__ int tmp[256];
    int t = threadIdx.x;
    int i = blockIdx.x * 256 + t;
    int v = (i < N) ? deg[i] : 0;
    tmp[t] = v;
    __syncthreads();
#pragma unroll
    for (int off = 1; off < 256; off <<= 1) {
        int x = (t >= off) ? tmp[t - off] : 0;
        __syncthreads();
        tmp[t] += x;
        __syncthreads();
    }
    int excl = tmp[t] - v + partials[blockIdx.x];
    if (i < N) { rowptr[i] = excl; woff[i] = excl; }
    if (blockIdx.x == 0 && t == 0) rowptr[N] = EE;
}

__global__ void scatter_kernel(const int* __restrict__ ei, int* __restrict__ woff,
                               int* __restrict__ esrc, int E, int EE) {
    int e = blockIdx.x * blockDim.x + threadIdx.x;
    if (e >= EE) return;
    int src, dst;
    if (e < E) { src = ei[e]; dst = ei[E + e]; } else { src = dst = e - E; }
    int slot = atomicAdd(&woff[dst], 1);
    esrc[slot] = src;
}

// ================= embed: h = x @ emb_W + emb_b + ntype_emb[node_types] =================
__global__ void embed_kernel(const float* __restrict__ x, const float* __restrict__ W,
                             const float* __restrict__ b, const float* __restrict__ nemb,
                             const int* __restrict__ ntypes, float* __restrict__ h, int N) {
    int t = threadIdx.x;           // 0..127
    int n0 = blockIdx.x * 4;
    __shared__ float xr[4][INDIM];
    for (int i = t; i < 4 * INDIM; i += 128) {
        int j = i >> 6, k = i & 63;
        int n = n0 + j;
        xr[j][k] = (n < N) ? x[n * INDIM + k] : 0.f;
    }
    __syncthreads();
    float acc[4] = {0.f, 0.f, 0.f, 0.f};
#pragma unroll 8
    for (int k = 0; k < INDIM; ++k) {
        float w = W[k * HID + t];
#pragma unroll
        for (int j = 0; j < 4; ++j) acc[j] += xr[j][k] * w;
    }
    float bb = b[t];
#pragma unroll
    for (int j = 0; j < 4; ++j) {
        int n = n0 + j;
        if (n < N) {
            int nt = ntypes[n];
            h[n * HID + t] = acc[j] + bb + nemb[nt * HID + t];
        }
    }
}

// ================= GAT projection + attention logits =================
__global__ void gemm_alpha_kernel(const float* __restrict__ h, const float* __restrict__ W,
                                  const float* __restrict__ asrc, const float* __restrict__ adst,
                                  float* __restrict__ hp, float* __restrict__ als,
                                  float* __restrict__ ald, int N) {
    int t = threadIdx.x;           // 0..127
    int n0 = blockIdx.x * 4;
    __shared__ float hr[4][HID];
#pragma unroll
    for (int j = 0; j < 4; ++j) {
        int n = n0 + j;
        hr[j][t] = (n < N) ? h[n * HID + t] : 0.f;
    }
    __syncthreads();
    float acc[4] = {0.f, 0.f, 0.f, 0.f};
#pragma unroll 8
    for (int k = 0; k < HID; ++k) {
        float w = W[k * HID + t];
#pragma unroll
        for (int j = 0; j < 4; ++j) acc[j] += hr[j][k] * w;
    }
    float as = asrc[t], ad = adst[t];
#pragma unroll
    for (int j = 0; j < 4; ++j) {
        int n = n0 + j;
        if (n >= N) continue;
        hp[n * HID + t] = acc[j];
        float ps = acc[j] * as;
        float pd = acc[j] * ad;
#pragma unroll
        for (int m = 8; m >= 1; m >>= 1) {
            ps += __shfl_xor(ps, m, 64);
            pd += __shfl_xor(pd, m, 64);
        }
        if ((t & 15) == 0) {
            int hd = t >> 4;
            als[n * HEADS + hd] = ps;
            ald[n * HEADS + hd] = pd;
        }
    }
}

// ================= fused aggregate: softmax + message sum + bias + LN + residual relu ===========
// one wave per dst node; lane owns channels (lane, lane+64); head denom identical across the
// 16 lanes of a head, so no reduction needed for it.
__global__ void gat_aggregate_kernel(const int* __restrict__ rowptr, const int* __restrict__ esrc,
                                     const float* __restrict__ als, const float* __restrict__ ald,
                                     const float* __restrict__ hp, const float* __restrict__ gb,
                                     const float* __restrict__ lg, const float* __restrict__ lb,
                                     float* __restrict__ h, int N) {
    int wave = threadIdx.x >> 6;
    int lane = threadIdx.x & 63;
    int n = blockIdx.x * 4 + wave;
    if (n >= N) return;
    int hd0 = lane >> 4, hd1 = hd0 + 4;
    int c0 = lane, c1 = lane + 64;
    float ad0 = ald[n * HEADS + hd0];
    float ad1 = ald[n * HEADS + hd1];
    int row = rowptr[n], end = rowptr[n + 1];   // end > row (self-loop guaranteed)
    float acc0 = 0.f, acc1 = 0.f, sw0 = 0.f, sw1 = 0.f;
    int src_next = esrc[row];
    for (int i = row; i < end; ++i) {
        int src = src_next;
        if (i + 1 < end) src_next = esrc[i + 1];
        float l0 = als[src * HEADS + hd0] + ad0;
        float l1 = als[src * HEADS + hd1] + ad1;
        l0 = l0 > 0.f ? l0 : 0.2f * l0;
        l1 = l1 > 0.f ? l1 : 0.2f * l1;
        float w0 = __expf(l0), w1 = __expf(l1);
        sw0 += w0; sw1 += w1;
        acc0 += w0 * hp[src * HID + c0];
        acc1 += w1 * hp[src * HID + c1];
    }
    float v0 = acc0 / sw0 + gb[c0];
    float v1 = acc1 / sw1 + gb[c1];
    // layernorm over 128 channels in-wave
    float sum = v0 + v1;
#pragma unroll
    for (int m = 32; m >= 1; m >>= 1) sum += __shfl_xor(sum, m, 64);
    float mu = sum * (1.f / 128.f);
    float d0 = v0 - mu, d1 = v1 - mu;
    float sq = d0 * d0 + d1 * d1;
#pragma unroll
    for (int m = 32; m >= 1; m >>= 1) sq += __shfl_xor(sq, m, 64);
    float inv = rsqrtf(sq * (1.f / 128.f) + 1e-5f);
    float y0 = d0 * inv * lg[c0] + lb[c0];
    float y1 = d1 * inv * lg[c1] + lb[c1];
    float r0 = y0 + h[n * HID + c0];
    float r1 = y1 + h[n * HID + c1];
    h[n * HID + c0] = r0 > 0.f ? r0 : 0.f;
    h[n * HID + c1] = r1 > 0.f ? r1 : 0.f;
}

// ================= global attention scores =================
__global__ void score_kernel(const float* __restrict__ h, const float* __restrict__ W1,
                             const float* __restrict__ b1, const float* __restrict__ W2,
                             const float* __restrict__ b2, float* __restrict__ escore, int N) {
    int t = threadIdx.x;           // 0..127
    int n0 = blockIdx.x * 4;
    __shared__ float hr[4][HID];
    __shared__ float part[4][2];
#pragma unroll
    for (int j = 0; j < 4; ++j) {
        int n = n0 + j;
        hr[j][t] = (n < N) ? h[n * HID + t] : 0.f;
    }
    __syncthreads();
    float acc[4];
#pragma unroll
    for (int j = 0; j < 4; ++j) acc[j] = b1[t];
#pragma unroll 8
    for (int k = 0; k < HID; ++k) {
        float w = W1[k * HID + t];
#pragma unroll
        for (int j = 0; j < 4; ++j) acc[j] += hr[j][k] * w;
    }
    float w2 = W2[t];
#pragma unroll
    for (int j = 0; j < 4; ++j) {
        float v = tanhf(acc[j]) * w2;
#pragma unroll
        for (int m = 32; m >= 1; m >>= 1) v += __shfl_xor(v, m, 64);
        if ((t & 63) == 0) part[j][t >> 6] = v;
    }
    __syncthreads();
    if (t < 4) {
        int n = n0 + t;
        if (n < N) escore[n] = expf(part[t][0] + part[t][1] + b2[0]);
    }
}

// ================= pooling =================
__global__ void pool_kernel(const float* __restrict__ h, const float* __restrict__ escore,
                            const int* __restrict__ batch, float* __restrict__ sums,
                            float* __restrict__ cnts, float* __restrict__ hgZ, int N) {
    __shared__ float lh[HID];
    __shared__ float lz;
    int t = threadIdx.x;
    if (t < HID) lh[t] = 0.f;
    if (t == 0) lz = 0.f;
    __syncthreads();
    int total = N * HID;
    int stride = gridDim.x * blockDim.x;
    for (int idx = blockIdx.x * blockDim.x + t; idx < total; idx += stride) {
        int n = idx >> 7, c = idx & 127;
        float hv = h[idx];
        float es = escore[n];
        atomicAdd(&lh[c], es * hv);
        int b = batch[n];
        atomicAdd(&sums[b * HID + c], hv);
        if (c == 0) {
            atomicAdd(&lz, es);
            atomicAdd(&cnts[b], 1.0f);
        }
    }
    __syncthreads();
    if (t < HID) atomicAdd(&hgZ[t], lh[t]);
    if (t == 0) atomicAdd(&hgZ[HID], lz);
}

// ================= classifier head =================
__global__ void head_kernel(const float* __restrict__ hgZ, const float* __restrict__ sums,
                            const float* __restrict__ cnts, const float* __restrict__ W1,
                            const float* __restrict__ b1, const float* __restrict__ W2,
                            const float* __restrict__ b2, float* __restrict__ out, int G) {
    int g = blockIdx.x;
    int t = threadIdx.x;
    __shared__ float hr[HID];
    __shared__ float part[2];
    float Z = hgZ[HID];
    float cnt = cnts[g];
    cnt = cnt > 1.f ? cnt : 1.f;
    hr[t] = hgZ[t] / Z + sums[g * HID + t] / cnt;
    __syncthreads();
    float acc = b1[t];
#pragma unroll 8
    for (int k = 0; k < HID; ++k) acc += hr[k] * W1[k * HID + t];
    acc = acc > 0.f ? acc : 0.f;
    float v = acc * W2[t];
#pragma unroll
    for (int m = 32; m >= 1; m >>= 1) v += __shfl_xor(v, m, 64);
    if ((t & 63) == 0) part[t >> 6] = v;
    __syncthreads();
    if (t == 0) out[g] = part[0] + part[1] + b2[0];
}

extern "C" void kernel_launch(void* const* d_in, const int* in_sizes, int n_in,
                              void* d_out, int out_size, void* d_ws, size_t ws_size,
                              hipStream_t stream) {
    const float* x        = (const float*)d_in[0];
    const int*   ei       = (const int*)d_in[1];
    const int*   ntypes   = (const int*)d_in[2];
    const int*   batch    = (const int*)d_in[3];
    const float* emb_W    = (const float*)d_in[4];
    const float* emb_b    = (const float*)d_in[5];
    const float* nemb     = (const float*)d_in[6];
    const float* gat_W    = (const float*)d_in[7];
    const float* att_src  = (const float*)d_in[8];
    const float* att_dst  = (const float*)d_in[9];
    const float* gat_b    = (const float*)d_in[10];
    const float* ln_g     = (const float*)d_in[11];
    const float* ln_b     = (const float*)d_in[12];
    const float* ga_W1    = (const float*)d_in[13];
    const float* ga_b1    = (const float*)d_in[14];
    const float* ga_W2    = (const float*)d_in[15];
    const float* ga_b2    = (const float*)d_in[16];
    const float* cls_W1   = (const float*)d_in[17];
    const float* cls_b1   = (const float*)d_in[18];
    const float* cls_W2   = (const float*)d_in[19];
    const float* cls_b2   = (const float*)d_in[20];
    float* out = (float*)d_out;

    const int N  = in_sizes[2];
    const int E  = in_sizes[1] / 2;
    const int EE = E + N;
    const int G  = out_size;
    const int NB = (N + 255) / 256;   // scan chunks

    float* ws      = (float*)d_ws;
    float* h       = ws;                               // N*128
    float* hp      = h + (size_t)N * HID;              // N*128
    float* als     = hp + (size_t)N * HID;             // N*8
    float* ald     = als + (size_t)N * HEADS;          // N*8
    float* escore  = ald + (size_t)N * HEADS;          // N
    float* sums    = escore + N;                       // G*128
    float* cnts    = sums + (size_t)G * HID;           // G
    float* hgZ     = cnts + G;                         // 129
    int*   ibase   = (int*)(hgZ + HID + 1);
    int*   rowptr  = ibase;                            // N+1
    int*   woff    = rowptr + (N + 1);                 // N
    int*   deg     = woff + N;                         // N
    int*   esrc    = deg + N;                          // EE
    int*   partials= esrc + EE;                        // NB

    // ---- CSR build ----
    hipMemsetAsync(deg, 0, (size_t)N * sizeof(int), stream);
    count_kernel<<<(EE + 255) / 256, 256, 0, stream>>>(ei, deg, E, EE);
    block_sum_kernel<<<NB, 256, 0, stream>>>(deg, partials, N);
    scan_partials_kernel<<<1, 64, 0, stream>>>(partials, NB);
    rowptr_kernel<<<NB, 256, 0, stream>>>(deg, partials, rowptr, woff, N, EE);
    scatter_kernel<<<(EE + 255) / 256, 256, 0, stream>>>(ei, woff, esrc, E, EE);

    // ---- network ----
    embed_kernel<<<(N + 3) / 4, 128, 0, stream>>>(x, emb_W, emb_b, nemb, ntypes, h, N);

    for (int l = 0; l < 3; ++l) {
        gemm_alpha_kernel<<<(N + 3) / 4, 128, 0, stream>>>(
            h, gat_W + (size_t)l * HID * HID, att_src + l * HID, att_dst + l * HID,
            hp, als, ald, N);
        gat_aggregate_kernel<<<(N + 3) / 4, 256, 0, stream>>>(
            rowptr, esrc, als, ald, hp, gat_b + l * HID, ln_g + l * HID, ln_b + l * HID, h, N);
    }

    score_kernel<<<(N + 3) / 4, 128, 0, stream>>>(h, ga_W1, ga_b1, ga_W2, ga_b2, escore, N);
    hipMemsetAsync(sums, 0, ((size_t)G * HID + G + HID + 1) * sizeof(float), stream);
    pool_kernel<<<512, 256, 0, stream>>>(h, escore, batch, sums, cnts, hgZ, N);
    head_kernel<<<G, 128, 0, stream>>>(hgZ, sums, cnts, cls_W1, cls_b1, cls_W2, cls_b2, out, G);
}